// Round 3
// baseline (64.633 us; speedup 1.0000x reference)
//
#include <hip/hip_runtime.h>

// Problem constants (match reference)
#define D_DIM 160
#define H_DIM 192
#define W_DIM 224
#define BLOCK 256
#define F4PT 40  // float4 per thread; 504 blocks cover one batch exactly

// Per batch: 160*192*224 voxels * 3 floats = 20,643,840 floats = 5,160,960 float4.
// 5,160,960 / (256 threads * 40 f4) = 504 blocks exactly. Grid = B*504 = 2016
// blocks @ 256 thr -> 7.875 blocks/CU, all co-resident (VGPR<=64 via launch
// bounds), equal work per block -> no scheduler tail.
//
// Stores are wave-unit-stride: thread writes float4 index f = base + tid + 256k
// (64 lanes x 16B contiguous = 1KB per store instruction).
// A float4 spans voxels v and v+1 (3 floats/voxel); phase p = (4f) mod 3.
// Voxel v+1's (x,y,z) = voxel v's + one of three wave-uniform deltas
// (step in W, W-wrap->H+1, or WH-wrap->D+1), selected per lane.
__global__ __launch_bounds__(BLOCK, 8) void AffineToDenseShift_kernel(
    const float* __restrict__ matrix, float* __restrict__ out,
    int blocks_per_batch) {
  const int b = blockIdx.x / blocks_per_batch;
  const int bx = blockIdx.x - b * blocks_per_batch;
  const float* M = matrix + b * 12;  // wave-uniform -> scalar loads

  const float a00 = M[0] - 1.0f, a01 = M[1],        a02 = M[2],         t0 = M[3];
  const float a10 = M[4],        a11 = M[5] - 1.0f, a12 = M[6],         t1 = M[7];
  const float a20 = M[8],        a21 = M[9],        a22 = M[10] - 1.0f, t2 = M[11];

  // Wave-uniform mesh deltas for voxel+1 in the three carry cases.
  const float cW = (float)(W_DIM - 1), cH = (float)(H_DIM - 1);
  const float dxW = a02,                       dyW = a12,                       dzW = a22;
  const float dxH = a01 - a02 * cW,            dyH = a11 - a12 * cW,            dzH = a21 - a22 * cW;
  const float dxD = a00 - a01 * cH - a02 * cW, dyD = a10 - a11 * cH - a12 * cW, dzD = a20 - a21 * cH - a22 * cW;

  const long long batch_floats = (long long)D_DIM * H_DIM * W_DIM * 3;
  float4* __restrict__ dst = (float4*)(out + (long long)b * batch_floats);

  const unsigned fbase = (unsigned)bx * (BLOCK * F4PT) + threadIdx.x;

  #pragma unroll 4
  for (int k = 0; k < F4PT; ++k) {
    const unsigned f = fbase + (unsigned)k * BLOCK;  // float4 index within batch
    const unsigned L = 4u * f;                       // first float index
    const unsigned v = L / 3u;                       // voxel index (magic-mul div)
    const unsigned p = L - 3u * v;                   // phase 0/1/2

    const unsigned w = v % (unsigned)W_DIM;
    const unsigned r = v / (unsigned)W_DIM;
    const unsigned h = r % (unsigned)H_DIM;
    const unsigned d = r / (unsigned)H_DIM;

    const float md = (float)d - (float)(D_DIM - 1) * 0.5f;
    const float mh = (float)h - (float)(H_DIM - 1) * 0.5f;
    const float mw = (float)w - (float)(W_DIM - 1) * 0.5f;

    // voxel v
    const float x0 = fmaf(a00, md, fmaf(a01, mh, fmaf(a02, mw, t0)));
    const float y0 = fmaf(a10, md, fmaf(a11, mh, fmaf(a12, mw, t1)));
    const float z0 = fmaf(a20, md, fmaf(a21, mh, fmaf(a22, mw, t2)));

    // voxel v+1 = voxel v + uniform delta selected by carry case
    const bool ww = (w == (unsigned)(W_DIM - 1));
    const bool hw = ww && (h == (unsigned)(H_DIM - 1));
    const float x1 = x0 + (ww ? (hw ? dxD : dxH) : dxW);
    const float y1 = y0 + (ww ? (hw ? dyD : dyH) : dyW);
    const float z1 = z0 + (ww ? (hw ? dzD : dzH) : dzW);

    float4 o;
    o.x = (p == 0u) ? x0 : ((p == 1u) ? y0 : z0);
    o.y = (p == 0u) ? y0 : ((p == 1u) ? z0 : x1);
    o.z = (p == 0u) ? z0 : ((p == 1u) ? x1 : y1);
    o.w = (p == 0u) ? x1 : ((p == 1u) ? y1 : z1);
    dst[f] = o;
  }
}

extern "C" void kernel_launch(void* const* d_in, const int* in_sizes, int n_in,
                              void* d_out, int out_size, void* d_ws, size_t ws_size,
                              hipStream_t stream) {
  const float* matrix = (const float*)d_in[0];
  float* out = (float*)d_out;

  const int batch = in_sizes[0] / 12;  // [B,3,4] fp32
  const long long batch_f4 = (long long)D_DIM * H_DIM * W_DIM * 3 / 4;   // 5,160,960
  const int blocks_per_batch = (int)(batch_f4 / ((long long)BLOCK * F4PT));  // 504, exact

  dim3 grid(blocks_per_batch * batch);
  AffineToDenseShift_kernel<<<grid, BLOCK, 0, stream>>>(matrix, out, blocks_per_batch);
}

// Round 4
// 59.506 us; speedup vs baseline: 1.0862x; 1.0862x over previous
//
#include <hip/hip_runtime.h>

// Problem constants (match reference)
#define D_DIM 160
#define H_DIM 192
#define W_DIM 224
#define BLOCK 256
#define S_ITERS 2   // super-iterations per block; block covers 2048 voxels

// out[b,d,h,w,i] = sum_j (A[b,i,j] - delta_ij) * mesh_j + t[b,i]
// mesh = (d - 79.5, h - 95.5, w - 111.5)
//
// Structure: per super-iteration a block covers 1024 consecutive voxels
// (= 3072 floats = 768 float4). Each thread computes 4 CONSECUTIVE voxels
// (4 | 224 so they never cross a row: one %224/%192 chain, 9 fma, 9 adds,
// no div-by-3, no phase cndmasks), writes its 12 floats to LDS, then after
// a barrier the block re-reads unit-stride float4s and stores them fully
// coalesced (64 lanes x 16B contiguous per store instruction).
// Grid geometry = round-2 winner: 3360 x B blocks, 24KB written per block.
__global__ __launch_bounds__(BLOCK) void AffineToDenseShift_kernel(
    const float* __restrict__ matrix, float* __restrict__ out) {
  __shared__ alignas(16) float lds[3 * 1024];  // 12,288 B

  const int b = blockIdx.y;
  const float* M = matrix + b * 12;  // wave-uniform -> scalar loads

  const float a00 = M[0] - 1.0f, a01 = M[1],        a02 = M[2],         t0 = M[3];
  const float a10 = M[4],        a11 = M[5] - 1.0f, a12 = M[6],         t1 = M[7];
  const float a20 = M[8],        a21 = M[9],        a22 = M[10] - 1.0f, t2 = M[11];

  const long long batch_floats = (long long)D_DIM * H_DIM * W_DIM * 3;
  float4* __restrict__ dst4 = (float4*)(out + (long long)b * batch_floats);

  const unsigned t = threadIdx.x;
  const unsigned vbase0 = blockIdx.x * (1024u * S_ITERS) + 4u * t;
  const unsigned f4base0 = blockIdx.x * (768u * S_ITERS) + t;

  float4* const Lw = (float4*)&lds[12u * t];

  #pragma unroll
  for (int s = 0; s < S_ITERS; ++s) {
    const unsigned v = vbase0 + (unsigned)s * 1024u;  // first of 4 consecutive voxels

    const unsigned w = v % (unsigned)W_DIM;           // magic-mul div chain
    const unsigned r = v / (unsigned)W_DIM;
    const unsigned h = r % (unsigned)H_DIM;
    const unsigned d = r / (unsigned)H_DIM;

    const float md = (float)d - (float)(D_DIM - 1) * 0.5f;
    const float mh = (float)h - (float)(H_DIM - 1) * 0.5f;
    const float mw = (float)w - (float)(W_DIM - 1) * 0.5f;

    const float x0 = fmaf(a00, md, fmaf(a01, mh, fmaf(a02, mw, t0)));
    const float y0 = fmaf(a10, md, fmaf(a11, mh, fmaf(a12, mw, t1)));
    const float z0 = fmaf(a20, md, fmaf(a21, mh, fmaf(a22, mw, t2)));
    // 3 more voxels along w (same row guaranteed): += column-2 of (A - I)
    const float x1 = x0 + a02, y1 = y0 + a12, z1 = z0 + a22;
    const float x2 = x1 + a02, y2 = y1 + a12, z2 = z1 + a22;
    const float x3 = x2 + a02, y3 = y2 + a12, z3 = z2 + a22;

    Lw[0] = make_float4(x0, y0, z0, x1);
    Lw[1] = make_float4(y1, z1, x2, y2);
    Lw[2] = make_float4(z2, x3, y3, z3);
    __syncthreads();

    // Coalesced drain: 768 float4 = 3 per thread, unit-stride across the block.
    const float4* const Ls = (const float4*)lds;
    float4* const dc = dst4 + (f4base0 + (unsigned)s * 768u - t);  // block chunk base
    dc[t]        = Ls[t];
    dc[t + 256u] = Ls[t + 256u];
    dc[t + 512u] = Ls[t + 512u];
    __syncthreads();  // protect LDS overwrite next super-iter
  }
}

extern "C" void kernel_launch(void* const* d_in, const int* in_sizes, int n_in,
                              void* d_out, int out_size, void* d_ws, size_t ws_size,
                              hipStream_t stream) {
  const float* matrix = (const float*)d_in[0];
  float* out = (float*)d_out;

  const int batch = in_sizes[0] / 12;  // [B,3,4] fp32
  const long long per_batch_vox = (long long)D_DIM * H_DIM * W_DIM;       // 6,881,280
  const int blocks_x = (int)(per_batch_vox / (1024LL * S_ITERS));         // 3360, exact

  dim3 grid(blocks_x, batch);
  AffineToDenseShift_kernel<<<grid, BLOCK, 0, stream>>>(matrix, out);
}